// Round 6
// baseline (3259.346 us; speedup 1.0000x reference)
//
#include <hip/hip_runtime.h>
#include <cstdint>
#include <cstddef>

// Problem constants
#define B_    16
#define N_    4096
#define S_    1024     // NPOINT
#define K_    32       // NSAMPLE
#define CNT_F 524288.0f   // B*S*K
#define EPS_  1e-5f

// Workspace layout (bytes). Total ~188 MB.
#define OFF_NXYZ 0u                    // [B][S][3] f32              196,608
#define OFF_IDX  196608u               // [B][S][K] i32            2,097,152
#define OFF_PTST 2293760u              // [B][N][68] f32 (xyz|pts|0) 17,825,792
#define OFF_PRE  20119552u             // [BS][32][64] f16          67,108,864
#define OFF_PRE2 87228416u             // [BS][32][64] f16          67,108,864
#define OFF_PART 154337280u            // [BS][256] f32             16,777,216
#define OFF_MM3  171114496u            // [BS][2][128] f32          16,777,216
#define OFF_ACC  187891712u            // [3][256] f32                   3,072

// ---------------------------------------------------------------------------
// Transpose xyz[B,3,N] + points[B,64,N] -> ptsT[B,N,68] (col 67 = 0 pad)
// ---------------------------------------------------------------------------
__global__ __launch_bounds__(256) void transpose_kernel(
    const float* __restrict__ xyz, const float* __restrict__ pts,
    float* __restrict__ ptsT) {
  __shared__ float tile[64 * 69];
  int blk = blockIdx.x;
  int b = blk >> 6;
  int n0 = (blk & 63) << 6;
  int t = threadIdx.x;
  int wave = t >> 6, ln = t & 63;
  int n = n0 + ln;
  for (int cc = wave; cc < 68; cc += 4) {
    float v;
    if (cc < 3)       v = xyz[(size_t)(b * 3 + cc) * N_ + n];
    else if (cc < 67) v = pts[(size_t)(b * 64 + (cc - 3)) * N_ + n];
    else              v = 0.f;
    tile[ln * 69 + cc] = v;
  }
  __syncthreads();
  for (int f = t; f < 64 * 68; f += 256) {
    int r = f / 68, c = f - r * 68;
    ptsT[(size_t)(b * N_ + n0 + r) * 68 + c] = tile[r * 69 + c];
  }
}

// ---------------------------------------------------------------------------
// Farthest point sampling. PROVEN selection-exact (Output 0 passes R1-R5).
// DO NOT MODIFY.
// ---------------------------------------------------------------------------
__global__ __launch_bounds__(512) void fps_kernel(
    const float* __restrict__ xyz, float* __restrict__ nxyz,
    float* __restrict__ out0) {
#pragma clang fp contract(off)
  __shared__ float sx[N_], sy[N_], sz[N_];
  __shared__ float redv[2][8];
  __shared__ int   redi[2][8];
  int b = blockIdx.x;
  int t = threadIdx.x;
  const float* xb = xyz + (size_t)b * 3 * N_;
  int i0 = t * 8;
  float xr[8], yr[8], zr[8], dist[8];
  {
    float4 v0 = *(const float4*)(xb + i0);
    float4 v1 = *(const float4*)(xb + i0 + 4);
    xr[0]=v0.x; xr[1]=v0.y; xr[2]=v0.z; xr[3]=v0.w;
    xr[4]=v1.x; xr[5]=v1.y; xr[6]=v1.z; xr[7]=v1.w;
    v0 = *(const float4*)(xb + N_ + i0);
    v1 = *(const float4*)(xb + N_ + i0 + 4);
    yr[0]=v0.x; yr[1]=v0.y; yr[2]=v0.z; yr[3]=v0.w;
    yr[4]=v1.x; yr[5]=v1.y; yr[6]=v1.z; yr[7]=v1.w;
    v0 = *(const float4*)(xb + 2 * N_ + i0);
    v1 = *(const float4*)(xb + 2 * N_ + i0 + 4);
    zr[0]=v0.x; zr[1]=v0.y; zr[2]=v0.z; zr[3]=v0.w;
    zr[4]=v1.x; zr[5]=v1.y; zr[6]=v1.z; zr[7]=v1.w;
  }
  for (int j = 0; j < 8; ++j) {
    sx[i0 + j] = xr[j]; sy[i0 + j] = yr[j]; sz[i0 + j] = zr[j];
    dist[j] = 1e10f;
  }
  __syncthreads();

  int far = 0, par = 0;
  for (int s = 0; s < S_; ++s) {
    float cx = sx[far], cy = sy[far], cz = sz[far];
    if (t == 0) {
      out0[b * 3 * S_ + s]          = cx;
      out0[b * 3 * S_ + S_ + s]     = cy;
      out0[b * 3 * S_ + 2 * S_ + s] = cz;
      float* nx = nxyz + ((size_t)b * S_ + s) * 3;
      nx[0] = cx; nx[1] = cy; nx[2] = cz;
    }
    float bv = -1.f;
    int bi = 0;
#pragma unroll
    for (int j = 0; j < 8; ++j) {
      float dx = xr[j] - cx, dy = yr[j] - cy, dz = zr[j] - cz;
      float d = dx * dx + dy * dy + dz * dz;
      float nd = fminf(dist[j], d);
      dist[j] = nd;
      if (nd > bv) { bv = nd; bi = i0 + j; }
    }
#pragma unroll
    for (int m = 1; m < 64; m <<= 1) {
      float ov = __shfl_xor(bv, m);
      int   oi = __shfl_xor(bi, m);
      if (ov > bv || (ov == bv && oi < bi)) { bv = ov; bi = oi; }
    }
    if ((t & 63) == 0) { redv[par][t >> 6] = bv; redi[par][t >> 6] = bi; }
    __syncthreads();
    bv = redv[par][0]; bi = redi[par][0];
#pragma unroll
    for (int w = 1; w < 8; ++w) {
      float ov = redv[par][w]; int oi = redi[par][w];
      if (ov > bv || (ov == bv && oi < bi)) { bv = ov; bi = oi; }
    }
    far = bi;
    par ^= 1;
  }
}

// ---------------------------------------------------------------------------
// Ball query R6: f32 with FMA CONTRACTION EVERYWHERE (XLA-CPU llvm.fmuladd
// emission hypothesis):
//   A  = fmaf(cz,cz, fmaf(cy,cy, cx*cx))        (fused reduce of square)
//   Bv = fmaf(z,z,  fmaf(y,y,  x*x))
//   dot= fmaf(cz,z, fmaf(cy,y, cx*x))           (Eigen/LLVM dot, k asc)
//   d  = fmaf(-2, dot, A + Bv)                  (contracted sub(add, mul))
//   in-ball iff d <= 0.04f.
// Evidence base: R1(asc)/R2(desc)/R3(fma-dot-only)/R4-R5(f64=truth) all fail
// IDENTICALLY -> ref is f32 with an untried order; this is the prime one.
// First K ascending; pad with first in-ball index. Thread per query.
// ---------------------------------------------------------------------------
__global__ __launch_bounds__(64) void bq_fma_kernel(
    const float* __restrict__ xyz, const float* __restrict__ nxyz,
    int* __restrict__ idxb) {
#pragma clang fp contract(off)
  int q = blockIdx.x * 64 + threadIdx.x;
  int b = q >> 10;
  const float* xb = xyz + (size_t)b * 3 * N_;
  float cx = nxyz[(size_t)q * 3];
  float cy = nxyz[(size_t)q * 3 + 1];
  float cz = nxyz[(size_t)q * 3 + 2];
  float A = fmaf(cz, cz, fmaf(cy, cy, cx * cx));
  int* out = idxb + (size_t)q * K_;
  int found = 0, first_i = -1;
  for (int i = 0; i < N_; ++i) {
    float x = xb[i], y = xb[N_ + i], z = xb[2 * N_ + i];
    float Bv  = fmaf(z, z, fmaf(y, y, x * x));
    float dot = fmaf(cz, z, fmaf(cy, y, cx * x));
    float d = fmaf(-2.0f, dot, A + Bv);
    if (d <= 0.04f) {
      if (first_i < 0) first_i = i;
      out[found] = i;
      ++found;
      if (found >= K_) break;
    }
  }
  for (int s = found; s < K_; ++s) out[s] = first_i;
}

// ---------------------------------------------------------------------------
// Layer 0: block per group, thread per out-channel (64). Plain dot over 67.
// ---------------------------------------------------------------------------
__global__ __launch_bounds__(64) void l0_kernel(
    const float* __restrict__ ptsT, const float* __restrict__ nxyz,
    const int* __restrict__ idxb, const float* __restrict__ w0,
    const float* __restrict__ b0, _Float16* __restrict__ pre,
    float* __restrict__ part) {
  __shared__ float sw2[67 * 64];   // [ci][o]
  __shared__ int sidx[32];
  __shared__ float sctr[3];
  int g = blockIdx.x;
  int o = threadIdx.x;
  int b = g >> 10;
  if (o < 32) sidx[o] = idxb[(size_t)g * K_ + o];
  if (o < 3)  sctr[o] = nxyz[(size_t)g * 3 + o];
  for (int f = o; f < 67 * 64; f += 64) {
    int ci = f >> 6, oo = f & 63;
    sw2[ci * 64 + oo] = w0[oo * 67 + ci];
  }
  __syncthreads();
  float bias = b0[o];
  float s1 = 0.f, s2 = 0.f;
  for (int k = 0; k < K_; ++k) {
    const float* row = ptsT + (size_t)(b * N_ + sidx[k]) * 68;
    float accv = 0.f;
    for (int ci = 0; ci < 3; ++ci)  accv += (row[ci] - sctr[ci]) * sw2[ci * 64 + o];
    for (int ci = 3; ci < 67; ++ci) accv += row[ci] * sw2[ci * 64 + o];
    float v = accv + bias;
    pre[(size_t)g * 2048 + k * 64 + o] = (_Float16)v;
    s1 += v; s2 += v * v;
  }
  part[(size_t)g * 256 + o] = s1;
  part[(size_t)g * 256 + 64 + o] = s2;
}

// ---------------------------------------------------------------------------
// Per-channel column-sum: block c sums part[:, c] over 16384 rows -> accum[c].
// ---------------------------------------------------------------------------
__global__ __launch_bounds__(256) void red_kernel(
    const float* __restrict__ part, float* __restrict__ accum) {
  __shared__ float red[256];
  int c = blockIdx.x;
  float a = 0.f;
  for (int r = threadIdx.x; r < B_ * S_; r += 256)
    a += part[(size_t)r * 256 + c];
  red[threadIdx.x] = a;
  __syncthreads();
  for (int m = 128; m > 0; m >>= 1) {
    if (threadIdx.x < m) red[threadIdx.x] += red[threadIdx.x + m];
    __syncthreads();
  }
  if (threadIdx.x == 0) accum[c] = red[0];
}

// ---------------------------------------------------------------------------
// Layer 1: BN0+relu on read, plain dot over 64, separate out buffer.
// ---------------------------------------------------------------------------
__global__ __launch_bounds__(64) void l1_kernel(
    const _Float16* __restrict__ pre, const float* __restrict__ accum,
    const float* __restrict__ gam, const float* __restrict__ bet,
    const float* __restrict__ w1, const float* __restrict__ b1,
    _Float16* __restrict__ pre2, float* __restrict__ part) {
  __shared__ float sw2[64 * 64];   // [ci][o]
  __shared__ float sin_[64];
  __shared__ float ssc[64], ssh[64];
  int g = blockIdx.x;
  int o = threadIdx.x;
  {
    float mu = accum[o] * (1.f / CNT_F);
    float var = accum[64 + o] * (1.f / CNT_F) - mu * mu;
    float sc = gam[o] / sqrtf(var + EPS_);
    ssc[o] = sc; ssh[o] = bet[o] - mu * sc;
  }
  for (int f = o; f < 64 * 64; f += 64) {
    int ci = f >> 6, oo = f & 63;
    sw2[ci * 64 + oo] = w1[oo * 64 + ci];
  }
  __syncthreads();
  float bias = b1[o];
  float s1 = 0.f, s2 = 0.f;
  for (int k = 0; k < K_; ++k) {
    float vi = (float)pre[(size_t)g * 2048 + k * 64 + o] * ssc[o] + ssh[o];
    sin_[o] = fmaxf(vi, 0.f);
    __syncthreads();
    float accv = 0.f;
    for (int ci = 0; ci < 64; ++ci) accv += sin_[ci] * sw2[ci * 64 + o];
    float v = accv + bias;
    pre2[(size_t)g * 2048 + k * 64 + o] = (_Float16)v;
    s1 += v; s2 += v * v;
    __syncthreads();
  }
  part[(size_t)g * 256 + o] = s1;
  part[(size_t)g * 256 + 64 + o] = s2;
}

// ---------------------------------------------------------------------------
// Layer 2 + pool prep: 128 threads. Stats + pre-BN max/min over k.
// ---------------------------------------------------------------------------
__global__ __launch_bounds__(128) void l2_kernel(
    const _Float16* __restrict__ pre2, const float* __restrict__ accum,
    const float* __restrict__ gam, const float* __restrict__ bet,
    const float* __restrict__ w2, const float* __restrict__ b2,
    float* __restrict__ mm, float* __restrict__ part) {
  __shared__ float sw2[64 * 128];   // [ci][o]
  __shared__ float sin_[64];
  __shared__ float ssc[64], ssh[64];
  int g = blockIdx.x;
  int t = threadIdx.x;
  if (t < 64) {
    float mu = accum[t] * (1.f / CNT_F);
    float var = accum[64 + t] * (1.f / CNT_F) - mu * mu;
    float sc = gam[t] / sqrtf(var + EPS_);
    ssc[t] = sc; ssh[t] = bet[t] - mu * sc;
  }
  for (int f = t; f < 64 * 128; f += 128) {
    int ci = f >> 7, oo = f & 127;
    sw2[ci * 128 + oo] = w2[oo * 64 + ci];
  }
  __syncthreads();
  float bias = b2[t];
  float s1 = 0.f, s2 = 0.f, mx = -3.4e38f, mn = 3.4e38f;
  for (int k = 0; k < K_; ++k) {
    if (t < 64) {
      float vi = (float)pre2[(size_t)g * 2048 + k * 64 + t] * ssc[t] + ssh[t];
      sin_[t] = fmaxf(vi, 0.f);
    }
    __syncthreads();
    float accv = 0.f;
    for (int ci = 0; ci < 64; ++ci) accv += sin_[ci] * sw2[ci * 128 + t];
    float v = accv + bias;
    s1 += v; s2 += v * v;
    mx = fmaxf(mx, v); mn = fminf(mn, v);
    __syncthreads();
  }
  part[(size_t)g * 256 + t] = s1;
  part[(size_t)g * 256 + 128 + t] = s2;
  mm[(size_t)g * 256 + t] = mx;
  mm[(size_t)g * 256 + 128 + t] = mn;
}

// ---------------------------------------------------------------------------
// Final: BN2 + relu on group max (min if scale<0), write out[B,128,S].
// ---------------------------------------------------------------------------
__global__ __launch_bounds__(256) void fin_kernel(
    const float* __restrict__ mm, const float* __restrict__ accum,
    const float* __restrict__ gam, const float* __restrict__ bet,
    float* __restrict__ out1) {
  int id = blockIdx.x * 256 + threadIdx.x;   // id = b*131072 + c*1024 + s
  int b = id >> 17;
  int c = (id >> 10) & 127;
  int s = id & 1023;
  float mu = accum[c] * (1.f / CNT_F);
  float var = accum[128 + c] * (1.f / CNT_F) - mu * mu;
  float sc = gam[c] / sqrtf(var + EPS_);
  float sh = bet[c] - mu * sc;
  int g = b * S_ + s;
  float v = (sc >= 0.f) ? mm[(size_t)g * 256 + c] : mm[(size_t)g * 256 + 128 + c];
  out1[id] = fmaxf(v * sc + sh, 0.f);
}

// ---------------------------------------------------------------------------
extern "C" void kernel_launch(void* const* d_in, const int* in_sizes, int n_in,
                              void* d_out, int out_size, void* d_ws, size_t ws_size,
                              hipStream_t stream) {
  const float* xyz = (const float*)d_in[0];
  const float* pts = (const float*)d_in[1];
  const float* w0  = (const float*)d_in[2];
  const float* b0  = (const float*)d_in[3];
  const float* g0  = (const float*)d_in[4];
  const float* bt0 = (const float*)d_in[5];
  const float* w1  = (const float*)d_in[6];
  const float* b1  = (const float*)d_in[7];
  const float* g1  = (const float*)d_in[8];
  const float* bt1 = (const float*)d_in[9];
  const float* w2  = (const float*)d_in[10];
  const float* b2  = (const float*)d_in[11];
  const float* g2  = (const float*)d_in[12];
  const float* bt2 = (const float*)d_in[13];
  float* out = (float*)d_out;

  char* ws = (char*)d_ws;
  float*    nxyz  = (float*)(ws + OFF_NXYZ);
  int*      idxb  = (int*)(ws + OFF_IDX);
  float*    ptsT  = (float*)(ws + OFF_PTST);
  _Float16* pre   = (_Float16*)(ws + OFF_PRE);
  _Float16* pre2  = (_Float16*)(ws + OFF_PRE2);
  float*    part  = (float*)(ws + OFF_PART);
  float*    mm    = (float*)(ws + OFF_MM3);
  float*    accum = (float*)(ws + OFF_ACC);

  fps_kernel<<<B_, 512, 0, stream>>>(xyz, nxyz, out);
  transpose_kernel<<<B_ * (N_ / 64), 256, 0, stream>>>(xyz, pts, ptsT);
  bq_fma_kernel<<<(B_ * S_) / 64, 64, 0, stream>>>(xyz, nxyz, idxb);

  l0_kernel<<<B_ * S_, 64, 0, stream>>>(ptsT, nxyz, idxb, w0, b0, pre, part);
  red_kernel<<<256, 256, 0, stream>>>(part, accum);
  l1_kernel<<<B_ * S_, 64, 0, stream>>>(pre, accum, g0, bt0, w1, b1, pre2, part);
  red_kernel<<<256, 256, 0, stream>>>(part, accum + 256);
  l2_kernel<<<B_ * S_, 128, 0, stream>>>(pre2, accum + 256, g1, bt1, w2, b2, mm, part);
  red_kernel<<<256, 256, 0, stream>>>(part, accum + 512);
  fin_kernel<<<(B_ * 128 * S_) / 256, 256, 0, stream>>>(mm, accum + 512, g2, bt2,
                                                        out + B_ * 3 * S_);
}

// Round 7
// 2855.599 us; speedup vs baseline: 1.1414x; 1.1414x over previous
//
#include <hip/hip_runtime.h>
#include <cstdint>
#include <cstddef>

// Problem constants
#define B_    16
#define N_    4096
#define S_    1024     // NPOINT
#define K_    32       // NSAMPLE
#define CNT_F 524288.0f   // B*S*K
#define EPS_  1e-5f

// Workspace layout (bytes). Total ~188 MB.
#define OFF_NXYZ 0u                    // [B][S][3] f32              196,608
#define OFF_IDX  196608u               // [B][S][K] i32            2,097,152
#define OFF_PTST 2293760u              // [B][N][68] f32 (xyz|pts|0) 17,825,792
#define OFF_PRE  20119552u             // [BS][32][64] f16          67,108,864
#define OFF_PRE2 87228416u             // [BS][32][64] f16          67,108,864
#define OFF_PART 154337280u            // [BS][256] f32             16,777,216
#define OFF_MM3  171114496u            // [BS][2][128] f32          16,777,216
#define OFF_ACC  187891712u            // [3][256] f32                   3,072

// ---------------------------------------------------------------------------
// Transpose xyz[B,3,N] + points[B,64,N] -> ptsT[B,N,68] (col 67 = 0 pad)
// ---------------------------------------------------------------------------
__global__ __launch_bounds__(256) void transpose_kernel(
    const float* __restrict__ xyz, const float* __restrict__ pts,
    float* __restrict__ ptsT) {
  __shared__ float tile[64 * 69];
  int blk = blockIdx.x;
  int b = blk >> 6;
  int n0 = (blk & 63) << 6;
  int t = threadIdx.x;
  int wave = t >> 6, ln = t & 63;
  int n = n0 + ln;
  for (int cc = wave; cc < 68; cc += 4) {
    float v;
    if (cc < 3)       v = xyz[(size_t)(b * 3 + cc) * N_ + n];
    else if (cc < 67) v = pts[(size_t)(b * 64 + (cc - 3)) * N_ + n];
    else              v = 0.f;
    tile[ln * 69 + cc] = v;
  }
  __syncthreads();
  for (int f = t; f < 64 * 68; f += 256) {
    int r = f / 68, c = f - r * 68;
    ptsT[(size_t)(b * N_ + n0 + r) * 68 + c] = tile[r * 69 + c];
  }
}

// ---------------------------------------------------------------------------
// FPS v2. Selection arithmetic UNCHANGED (proven exact R1-R6). R7 change:
// centroid outputs staged in LDS, written coalesced after the loop. This
// removes the per-iteration global stores whose vmcnt(0) drain before
// s_barrier serialized an HBM store ack into all 1024 iterations.
// ---------------------------------------------------------------------------
__global__ __launch_bounds__(512) void fps_kernel(
    const float* __restrict__ xyz, float* __restrict__ nxyz,
    float* __restrict__ out0) {
#pragma clang fp contract(off)
  __shared__ float sx[N_], sy[N_], sz[N_];
  __shared__ float scent[S_ * 3];   // [s][3] interleaved
  __shared__ float redv[2][8];
  __shared__ int   redi[2][8];
  int b = blockIdx.x;
  int t = threadIdx.x;
  const float* xb = xyz + (size_t)b * 3 * N_;
  int i0 = t * 8;
  float xr[8], yr[8], zr[8], dist[8];
  {
    float4 v0 = *(const float4*)(xb + i0);
    float4 v1 = *(const float4*)(xb + i0 + 4);
    xr[0]=v0.x; xr[1]=v0.y; xr[2]=v0.z; xr[3]=v0.w;
    xr[4]=v1.x; xr[5]=v1.y; xr[6]=v1.z; xr[7]=v1.w;
    v0 = *(const float4*)(xb + N_ + i0);
    v1 = *(const float4*)(xb + N_ + i0 + 4);
    yr[0]=v0.x; yr[1]=v0.y; yr[2]=v0.z; yr[3]=v0.w;
    yr[4]=v1.x; yr[5]=v1.y; yr[6]=v1.z; yr[7]=v1.w;
    v0 = *(const float4*)(xb + 2 * N_ + i0);
    v1 = *(const float4*)(xb + 2 * N_ + i0 + 4);
    zr[0]=v0.x; zr[1]=v0.y; zr[2]=v0.z; zr[3]=v0.w;
    zr[4]=v1.x; zr[5]=v1.y; zr[6]=v1.z; zr[7]=v1.w;
  }
  for (int j = 0; j < 8; ++j) {
    sx[i0 + j] = xr[j]; sy[i0 + j] = yr[j]; sz[i0 + j] = zr[j];
    dist[j] = 1e10f;
  }
  __syncthreads();

  int far = 0, par = 0;
  for (int s = 0; s < S_; ++s) {
    float cx = sx[far], cy = sy[far], cz = sz[far];
    if (t == 0) {
      scent[s * 3]     = cx;   // LDS only -- no vmcnt traffic in loop
      scent[s * 3 + 1] = cy;
      scent[s * 3 + 2] = cz;
    }
    float bv = -1.f;
    int bi = 0;
#pragma unroll
    for (int j = 0; j < 8; ++j) {
      float dx = xr[j] - cx, dy = yr[j] - cy, dz = zr[j] - cz;
      float d = dx * dx + dy * dy + dz * dz;  // left-assoc, no fma
      float nd = fminf(dist[j], d);
      dist[j] = nd;
      if (nd > bv) { bv = nd; bi = i0 + j; }  // strict >: first index wins
    }
#pragma unroll
    for (int m = 1; m < 64; m <<= 1) {
      float ov = __shfl_xor(bv, m);
      int   oi = __shfl_xor(bi, m);
      if (ov > bv || (ov == bv && oi < bi)) { bv = ov; bi = oi; }
    }
    if ((t & 63) == 0) { redv[par][t >> 6] = bv; redi[par][t >> 6] = bi; }
    __syncthreads();
    bv = redv[par][0]; bi = redi[par][0];
#pragma unroll
    for (int w = 1; w < 8; ++w) {
      float ov = redv[par][w]; int oi = redi[par][w];
      if (ov > bv || (ov == bv && oi < bi)) { bv = ov; bi = oi; }
    }
    far = bi;
    par ^= 1;  // double-buffered red slots -> one barrier per iteration
  }
  __syncthreads();
  // Coalesced output writes from LDS staging.
  for (int f = t; f < 3 * S_; f += 512)
    nxyz[(size_t)b * 3 * S_ + f] = scent[f];        // [B][S][3]
  for (int s = t; s < S_; s += 512) {               // [B][3][S]
    out0[(size_t)b * 3 * S_ + s]          = scent[s * 3];
    out0[(size_t)b * 3 * S_ + S_ + s]     = scent[s * 3 + 1];
    out0[(size_t)b * 3 * S_ + 2 * S_ + s] = scent[s * 3 + 2];
  }
}

// ---------------------------------------------------------------------------
// Ball query: PROVEN EXACT in R6 (XLA-CPU f32 all-fma ordering). DO NOT
// MODIFY the arithmetic. Thread per query, serial scan, early break.
// ---------------------------------------------------------------------------
__global__ __launch_bounds__(64) void bq_fma_kernel(
    const float* __restrict__ xyz, const float* __restrict__ nxyz,
    int* __restrict__ idxb) {
#pragma clang fp contract(off)
  int q = blockIdx.x * 64 + threadIdx.x;
  int b = q >> 10;
  const float* xb = xyz + (size_t)b * 3 * N_;
  float cx = nxyz[(size_t)q * 3];
  float cy = nxyz[(size_t)q * 3 + 1];
  float cz = nxyz[(size_t)q * 3 + 2];
  float A = fmaf(cz, cz, fmaf(cy, cy, cx * cx));
  int* out = idxb + (size_t)q * K_;
  int found = 0, first_i = -1;
  for (int i = 0; i < N_; ++i) {
    float x = xb[i], y = xb[N_ + i], z = xb[2 * N_ + i];
    float Bv  = fmaf(z, z, fmaf(y, y, x * x));
    float dot = fmaf(cz, z, fmaf(cy, y, cx * x));
    float d = fmaf(-2.0f, dot, A + Bv);
    if (d <= 0.04f) {
      if (first_i < 0) first_i = i;
      out[found] = i;
      ++found;
      if (found >= K_) break;
    }
  }
  for (int s = found; s < K_; ++s) out[s] = first_i;
}

// ---------------------------------------------------------------------------
// Layer 0 conv (tiled, validated R2-R5 by identical-absmax equivalence):
// gather -> 32x67 @ 67x64 -> pre f16 + per-block channel sum/sumsq partials.
// 128 thr, 4x4 register tile, float4 LDS reads (strides 72/76).
// ---------------------------------------------------------------------------
__global__ __launch_bounds__(128) void convA_kernel(
    const float* __restrict__ ptsT, const float* __restrict__ nxyz,
    const int* __restrict__ idxb, const float* __restrict__ w0,
    const float* __restrict__ b0, _Float16* __restrict__ pre,
    float* __restrict__ part) {
  __shared__ __align__(16) float sfeat[32 * 72];
  __shared__ __align__(16) float sw[64 * 76];
  __shared__ float red0[64 * 8], red1[64 * 8];
  __shared__ __align__(16) _Float16 sstage[2048];
  __shared__ int sidx[32];
  int g = blockIdx.x;
  int t = threadIdx.x;
  int b = g >> 10;
  if (t < 32) sidx[t] = idxb[(size_t)g * K_ + t];
  for (int f = t; f < 64 * 68; f += 128) {
    int c = f / 68, ci = f - c * 68;
    sw[c * 76 + ci] = (ci < 67) ? w0[c * 67 + ci] : 0.f;
  }
  const float* nx = nxyz + (size_t)g * 3;
  float ctr0 = nx[0], ctr1 = nx[1], ctr2 = nx[2];
  __syncthreads();
  for (int f = t; f < 32 * 68; f += 128) {
    int k = f / 68, ci = f - k * 68;
    float v = ptsT[(size_t)(b * N_ + sidx[k]) * 68 + ci];  // col 67 is 0
    if (ci == 0) v -= ctr0; else if (ci == 1) v -= ctr1; else if (ci == 2) v -= ctr2;
    sfeat[k * 72 + ci] = v;
  }
  __syncthreads();
  int kq = t & 7, cq = t >> 3;
  float acc[4][4] = {};
  for (int ci = 0; ci < 68; ci += 4) {
    float4 fv[4], wv[4];
#pragma unroll
    for (int kk = 0; kk < 4; ++kk) fv[kk] = *(const float4*)&sfeat[(kq + 8 * kk) * 72 + ci];
#pragma unroll
    for (int cc = 0; cc < 4; ++cc) wv[cc] = *(const float4*)&sw[(cq + 16 * cc) * 76 + ci];
#pragma unroll
    for (int kk = 0; kk < 4; ++kk)
#pragma unroll
      for (int cc = 0; cc < 4; ++cc)
        acc[kk][cc] += fv[kk].x * wv[cc].x + fv[kk].y * wv[cc].y +
                       fv[kk].z * wv[cc].z + fv[kk].w * wv[cc].w;
  }
#pragma unroll
  for (int cc = 0; cc < 4; ++cc) {
    int c = cq + 16 * cc;
    float bias = b0[c];
    float s1 = 0.f, s2 = 0.f;
#pragma unroll
    for (int kk = 0; kk < 4; ++kk) {
      float v = acc[kk][cc] + bias;
      sstage[(kq + 8 * kk) * 64 + c] = (_Float16)v;
      s1 += v; s2 += v * v;
    }
    red0[c * 8 + kq] = s1; red1[c * 8 + kq] = s2;
  }
  __syncthreads();
  if (t < 64) {
    float s1 = 0.f, s2 = 0.f;
#pragma unroll
    for (int qn = 0; qn < 8; ++qn) { s1 += red0[t * 8 + qn]; s2 += red1[t * 8 + qn]; }
    part[(size_t)g * 256 + t] = s1;
    part[(size_t)g * 256 + 64 + t] = s2;
  }
  uint4* dst = (uint4*)(pre + (size_t)g * 2048);
  const uint4* srcv = (const uint4*)sstage;
  dst[t] = srcv[t];
  dst[t + 128] = srcv[t + 128];
}

// ---------------------------------------------------------------------------
// Per-channel column-sum: block c sums part[:, c] over 16384 rows -> accum[c].
// ---------------------------------------------------------------------------
__global__ __launch_bounds__(256) void red_kernel(
    const float* __restrict__ part, float* __restrict__ accum) {
  __shared__ float red[256];
  int c = blockIdx.x;
  float a = 0.f;
  for (int r = threadIdx.x; r < B_ * S_; r += 256)
    a += part[(size_t)r * 256 + c];
  red[threadIdx.x] = a;
  __syncthreads();
  for (int m = 128; m > 0; m >>= 1) {
    if (threadIdx.x < m) red[threadIdx.x] += red[threadIdx.x + m];
    __syncthreads();
  }
  if (threadIdx.x == 0) accum[c] = red[0];
}

// ---------------------------------------------------------------------------
// Layer 1 conv (tiled): BN0+relu on pre -> conv w1 -> pre2 + stats partials.
// ---------------------------------------------------------------------------
__global__ __launch_bounds__(128) void convB_kernel(
    const _Float16* __restrict__ pre, const float* __restrict__ accum,
    const float* __restrict__ gam, const float* __restrict__ bet,
    const float* __restrict__ w1, const float* __restrict__ b1,
    _Float16* __restrict__ pre2, float* __restrict__ part) {
  __shared__ __align__(16) float sfeat[32 * 72];
  __shared__ __align__(16) float sw[64 * 76];
  __shared__ float red0[64 * 8], red1[64 * 8];
  __shared__ __align__(16) _Float16 sstage[2048];
  __shared__ float ssc[64], ssh[64];
  int g = blockIdx.x;
  int t = threadIdx.x;
  if (t < 64) {
    float mu = accum[t] * (1.f / CNT_F);
    float var = accum[64 + t] * (1.f / CNT_F) - mu * mu;
    float sc = gam[t] / sqrtf(var + EPS_);
    ssc[t] = sc; ssh[t] = bet[t] - mu * sc;
  }
  for (int f = t; f < 64 * 64; f += 128) {
    int c = f >> 6, ci = f & 63;
    sw[c * 76 + ci] = w1[f];
  }
  __syncthreads();
  const _Float16* src = pre + (size_t)g * 2048;
  for (int f = t; f < 2048; f += 128) {
    int c = f & 63;
    float v = (float)src[f] * ssc[c] + ssh[c];
    sfeat[(f >> 6) * 72 + c] = fmaxf(v, 0.f);
  }
  __syncthreads();
  int kq = t & 7, cq = t >> 3;
  float acc[4][4] = {};
  for (int ci = 0; ci < 64; ci += 4) {
    float4 fv[4], wv[4];
#pragma unroll
    for (int kk = 0; kk < 4; ++kk) fv[kk] = *(const float4*)&sfeat[(kq + 8 * kk) * 72 + ci];
#pragma unroll
    for (int cc = 0; cc < 4; ++cc) wv[cc] = *(const float4*)&sw[(cq + 16 * cc) * 76 + ci];
#pragma unroll
    for (int kk = 0; kk < 4; ++kk)
#pragma unroll
      for (int cc = 0; cc < 4; ++cc)
        acc[kk][cc] += fv[kk].x * wv[cc].x + fv[kk].y * wv[cc].y +
                       fv[kk].z * wv[cc].z + fv[kk].w * wv[cc].w;
  }
#pragma unroll
  for (int cc = 0; cc < 4; ++cc) {
    int c = cq + 16 * cc;
    float bias = b1[c];
    float s1 = 0.f, s2 = 0.f;
#pragma unroll
    for (int kk = 0; kk < 4; ++kk) {
      float v = acc[kk][cc] + bias;
      sstage[(kq + 8 * kk) * 64 + c] = (_Float16)v;
      s1 += v; s2 += v * v;
    }
    red0[c * 8 + kq] = s1; red1[c * 8 + kq] = s2;
  }
  __syncthreads();
  if (t < 64) {
    float s1 = 0.f, s2 = 0.f;
#pragma unroll
    for (int qn = 0; qn < 8; ++qn) { s1 += red0[t * 8 + qn]; s2 += red1[t * 8 + qn]; }
    part[(size_t)g * 256 + t] = s1;
    part[(size_t)g * 256 + 64 + t] = s2;
  }
  uint4* dst = (uint4*)(pre2 + (size_t)g * 2048);
  const uint4* srcv = (const uint4*)sstage;
  dst[t] = srcv[t];
  dst[t + 128] = srcv[t + 128];
}

// ---------------------------------------------------------------------------
// Layer 2 conv (tiled): BN1+relu on pre2 -> conv w2 (128 out) -> stats
// partials + per-group pre-BN max/min over k (relu∘BN monotone).
// ---------------------------------------------------------------------------
__global__ __launch_bounds__(256) void convC_kernel(
    const _Float16* __restrict__ pre2, const float* __restrict__ accum,
    const float* __restrict__ gam, const float* __restrict__ bet,
    const float* __restrict__ w2, const float* __restrict__ b2,
    float* __restrict__ mm, float* __restrict__ part) {
  __shared__ __align__(16) float sfeat[32 * 72];
  __shared__ __align__(16) float sw[128 * 76];
  __shared__ float red0[128 * 8], red1[128 * 8];
  __shared__ float rmax[128 * 8], rmin[128 * 8];
  __shared__ float ssc[64], ssh[64];
  int g = blockIdx.x;
  int t = threadIdx.x;
  if (t < 64) {
    float mu = accum[t] * (1.f / CNT_F);
    float var = accum[64 + t] * (1.f / CNT_F) - mu * mu;
    float sc = gam[t] / sqrtf(var + EPS_);
    ssc[t] = sc; ssh[t] = bet[t] - mu * sc;
  }
  for (int f = t; f < 128 * 64; f += 256) {
    int c = f >> 6, ci = f & 63;
    sw[c * 76 + ci] = w2[f];
  }
  __syncthreads();
  const _Float16* src = pre2 + (size_t)g * 2048;
  for (int f = t; f < 2048; f += 256) {
    int c = f & 63;
    float v = (float)src[f] * ssc[c] + ssh[c];
    sfeat[(f >> 6) * 72 + c] = fmaxf(v, 0.f);
  }
  __syncthreads();
  int kq = t & 7, cq = t >> 3;  // cq 0..31
  float acc[4][4] = {};
  for (int ci = 0; ci < 64; ci += 4) {
    float4 fv[4], wv[4];
#pragma unroll
    for (int kk = 0; kk < 4; ++kk) fv[kk] = *(const float4*)&sfeat[(kq + 8 * kk) * 72 + ci];
#pragma unroll
    for (int cc = 0; cc < 4; ++cc) wv[cc] = *(const float4*)&sw[(cq + 32 * cc) * 76 + ci];
#pragma unroll
    for (int kk = 0; kk < 4; ++kk)
#pragma unroll
      for (int cc = 0; cc < 4; ++cc)
        acc[kk][cc] += fv[kk].x * wv[cc].x + fv[kk].y * wv[cc].y +
                       fv[kk].z * wv[cc].z + fv[kk].w * wv[cc].w;
  }
#pragma unroll
  for (int cc = 0; cc < 4; ++cc) {
    int c = cq + 32 * cc;
    float bias = b2[c];
    float s1 = 0.f, s2 = 0.f, mx = -3.4e38f, mn = 3.4e38f;
#pragma unroll
    for (int kk = 0; kk < 4; ++kk) {
      float v = acc[kk][cc] + bias;
      s1 += v; s2 += v * v;
      mx = fmaxf(mx, v); mn = fminf(mn, v);
    }
    red0[c * 8 + kq] = s1; red1[c * 8 + kq] = s2;
    rmax[c * 8 + kq] = mx; rmin[c * 8 + kq] = mn;
  }
  __syncthreads();
  if (t < 128) {
    float s1 = 0.f, s2 = 0.f, mx = -3.4e38f, mn = 3.4e38f;
#pragma unroll
    for (int qn = 0; qn < 8; ++qn) {
      s1 += red0[t * 8 + qn]; s2 += red1[t * 8 + qn];
      mx = fmaxf(mx, rmax[t * 8 + qn]); mn = fminf(mn, rmin[t * 8 + qn]);
    }
    part[(size_t)g * 256 + t] = s1;
    part[(size_t)g * 256 + 128 + t] = s2;
    mm[(size_t)g * 256 + t] = mx;
    mm[(size_t)g * 256 + 128 + t] = mn;
  }
}

// ---------------------------------------------------------------------------
// Final: BN2 + relu on group max (min if scale<0), write out[B,128,S].
// ---------------------------------------------------------------------------
__global__ __launch_bounds__(256) void fin_kernel(
    const float* __restrict__ mm, const float* __restrict__ accum,
    const float* __restrict__ gam, const float* __restrict__ bet,
    float* __restrict__ out1) {
  int id = blockIdx.x * 256 + threadIdx.x;   // id = b*131072 + c*1024 + s
  int b = id >> 17;
  int c = (id >> 10) & 127;
  int s = id & 1023;
  float mu = accum[c] * (1.f / CNT_F);
  float var = accum[128 + c] * (1.f / CNT_F) - mu * mu;
  float sc = gam[c] / sqrtf(var + EPS_);
  float sh = bet[c] - mu * sc;
  int g = b * S_ + s;
  float v = (sc >= 0.f) ? mm[(size_t)g * 256 + c] : mm[(size_t)g * 256 + 128 + c];
  out1[id] = fmaxf(v * sc + sh, 0.f);
}

// ---------------------------------------------------------------------------
extern "C" void kernel_launch(void* const* d_in, const int* in_sizes, int n_in,
                              void* d_out, int out_size, void* d_ws, size_t ws_size,
                              hipStream_t stream) {
  const float* xyz = (const float*)d_in[0];
  const float* pts = (const float*)d_in[1];
  const float* w0  = (const float*)d_in[2];
  const float* b0  = (const float*)d_in[3];
  const float* g0  = (const float*)d_in[4];
  const float* bt0 = (const float*)d_in[5];
  const float* w1  = (const float*)d_in[6];
  const float* b1  = (const float*)d_in[7];
  const float* g1  = (const float*)d_in[8];
  const float* bt1 = (const float*)d_in[9];
  const float* w2  = (const float*)d_in[10];
  const float* b2  = (const float*)d_in[11];
  const float* g2  = (const float*)d_in[12];
  const float* bt2 = (const float*)d_in[13];
  float* out = (float*)d_out;

  char* ws = (char*)d_ws;
  float*    nxyz  = (float*)(ws + OFF_NXYZ);
  int*      idxb  = (int*)(ws + OFF_IDX);
  float*    ptsT  = (float*)(ws + OFF_PTST);
  _Float16* pre   = (_Float16*)(ws + OFF_PRE);
  _Float16* pre2  = (_Float16*)(ws + OFF_PRE2);
  float*    part  = (float*)(ws + OFF_PART);
  float*    mm    = (float*)(ws + OFF_MM3);
  float*    accum = (float*)(ws + OFF_ACC);

  fps_kernel<<<B_, 512, 0, stream>>>(xyz, nxyz, out);
  transpose_kernel<<<B_ * (N_ / 64), 256, 0, stream>>>(xyz, pts, ptsT);
  bq_fma_kernel<<<(B_ * S_) / 64, 64, 0, stream>>>(xyz, nxyz, idxb);

  convA_kernel<<<B_ * S_, 128, 0, stream>>>(ptsT, nxyz, idxb, w0, b0, pre, part);
  red_kernel<<<256, 256, 0, stream>>>(part, accum);
  convB_kernel<<<B_ * S_, 128, 0, stream>>>(pre, accum, g0, bt0, w1, b1, pre2, part);
  red_kernel<<<256, 256, 0, stream>>>(part, accum + 256);
  convC_kernel<<<B_ * S_, 256, 0, stream>>>(pre2, accum + 256, g1, bt1, w2, b2, mm, part);
  red_kernel<<<256, 256, 0, stream>>>(part, accum + 512);
  fin_kernel<<<(B_ * 128 * S_) / 256, 256, 0, stream>>>(mm, accum + 512, g2, bt2,
                                                        out + B_ * 3 * S_);
}

// Round 8
// 2611.953 us; speedup vs baseline: 1.2479x; 1.0933x over previous
//
#include <hip/hip_runtime.h>
#include <cstdint>
#include <cstddef>

// Problem constants
#define B_    16
#define N_    4096
#define S_    1024     // NPOINT
#define K_    32       // NSAMPLE
#define CNT_F 524288.0f   // B*S*K
#define EPS_  1e-5f

// Workspace layout (bytes). Total ~188 MB.
#define OFF_NXYZ 0u                    // [B][S][3] f32              196,608
#define OFF_IDX  196608u               // [B][S][K] i32            2,097,152
#define OFF_PTST 2293760u              // [B][N][68] f32 (xyz|pts|0) 17,825,792
#define OFF_PRE  20119552u             // [BS][32][64] f16          67,108,864
#define OFF_PRE2 87228416u             // [BS][32][64] f16          67,108,864
#define OFF_PART 154337280u            // [BS][256] f32             16,777,216
#define OFF_MM3  171114496u            // [BS][2][128] f32          16,777,216
#define OFF_ACC  187891712u            // [3][256] f32                   3,072

// ---------------------------------------------------------------------------
// Transpose xyz[B,3,N] + points[B,64,N] -> ptsT[B,N,68] (col 67 = 0 pad)
// ---------------------------------------------------------------------------
__global__ __launch_bounds__(256) void transpose_kernel(
    const float* __restrict__ xyz, const float* __restrict__ pts,
    float* __restrict__ ptsT) {
  __shared__ float tile[64 * 69];
  int blk = blockIdx.x;
  int b = blk >> 6;
  int n0 = (blk & 63) << 6;
  int t = threadIdx.x;
  int wave = t >> 6, ln = t & 63;
  int n = n0 + ln;
  for (int cc = wave; cc < 68; cc += 4) {
    float v;
    if (cc < 3)       v = xyz[(size_t)(b * 3 + cc) * N_ + n];
    else if (cc < 67) v = pts[(size_t)(b * 64 + (cc - 3)) * N_ + n];
    else              v = 0.f;
    tile[ln * 69 + cc] = v;
  }
  __syncthreads();
  for (int f = t; f < 64 * 68; f += 256) {
    int r = f / 68, c = f - r * 68;
    ptsT[(size_t)(b * N_ + n0 + r) * 68 + c] = tile[r * 69 + c];
  }
}

// ---------------------------------------------------------------------------
// DPP argmax step: combine (bv,bi) with the DPP-shuffled lane pair. Argmax
// with min-index tie-break is associative+commutative, so a rotation network
// (ror 1,2,4,8 within 16-lane rows, then bcast15/31 across rows) leaves the
// full-wave winner in lane 63. VALU-only: no ds_swizzle latency.
// ---------------------------------------------------------------------------
template <int CTRL, int RM>
__device__ __forceinline__ void dpp_argmax_step(float& bv, int& bi) {
  int ovi = __builtin_amdgcn_update_dpp(__float_as_int(bv), __float_as_int(bv),
                                        CTRL, RM, 0xf, false);
  int oi  = __builtin_amdgcn_update_dpp(bi, bi, CTRL, RM, 0xf, false);
  float ov = __int_as_float(ovi);
  if (ov > bv || (ov == bv && oi < bi)) { bv = ov; bi = oi; }
}

// ---------------------------------------------------------------------------
// FPS v3. Selection arithmetic UNCHANGED (proven exact R1-R7): f32,
// contract(off), d = (dx*dx+dy*dy)+dz*dz, strict->first-index argmax.
// R8: wave argmax via DPP rotation network (VALU) instead of 12 serial
// ds_swizzle shuffles; lane 63 publishes each wave's candidate.
// ---------------------------------------------------------------------------
__global__ __launch_bounds__(512) void fps_kernel(
    const float* __restrict__ xyz, float* __restrict__ nxyz,
    float* __restrict__ out0) {
#pragma clang fp contract(off)
  __shared__ float sx[N_], sy[N_], sz[N_];
  __shared__ float scent[S_ * 3];   // [s][3] interleaved
  __shared__ float redv[2][8];
  __shared__ int   redi[2][8];
  int b = blockIdx.x;
  int t = threadIdx.x;
  const float* xb = xyz + (size_t)b * 3 * N_;
  int i0 = t * 8;
  float xr[8], yr[8], zr[8], dist[8];
  {
    float4 v0 = *(const float4*)(xb + i0);
    float4 v1 = *(const float4*)(xb + i0 + 4);
    xr[0]=v0.x; xr[1]=v0.y; xr[2]=v0.z; xr[3]=v0.w;
    xr[4]=v1.x; xr[5]=v1.y; xr[6]=v1.z; xr[7]=v1.w;
    v0 = *(const float4*)(xb + N_ + i0);
    v1 = *(const float4*)(xb + N_ + i0 + 4);
    yr[0]=v0.x; yr[1]=v0.y; yr[2]=v0.z; yr[3]=v0.w;
    yr[4]=v1.x; yr[5]=v1.y; yr[6]=v1.z; yr[7]=v1.w;
    v0 = *(const float4*)(xb + 2 * N_ + i0);
    v1 = *(const float4*)(xb + 2 * N_ + i0 + 4);
    zr[0]=v0.x; zr[1]=v0.y; zr[2]=v0.z; zr[3]=v0.w;
    zr[4]=v1.x; zr[5]=v1.y; zr[6]=v1.z; zr[7]=v1.w;
  }
  for (int j = 0; j < 8; ++j) {
    sx[i0 + j] = xr[j]; sy[i0 + j] = yr[j]; sz[i0 + j] = zr[j];
    dist[j] = 1e10f;
  }
  __syncthreads();

  int far = 0, par = 0;
  for (int s = 0; s < S_; ++s) {
    float cx = sx[far], cy = sy[far], cz = sz[far];
    if (t == 0) {
      scent[s * 3]     = cx;
      scent[s * 3 + 1] = cy;
      scent[s * 3 + 2] = cz;
    }
    float bv = -1.f;
    int bi = 0;
#pragma unroll
    for (int j = 0; j < 8; ++j) {
      float dx = xr[j] - cx, dy = yr[j] - cy, dz = zr[j] - cz;
      float d = dx * dx + dy * dy + dz * dz;  // left-assoc, no fma
      float nd = fminf(dist[j], d);
      dist[j] = nd;
      if (nd > bv) { bv = nd; bi = i0 + j; }  // strict >: first index wins
    }
    // Wave argmax: rotation network within rows, then cross-row broadcasts.
    dpp_argmax_step<0x121, 0xf>(bv, bi);  // row_ror:1
    dpp_argmax_step<0x122, 0xf>(bv, bi);  // row_ror:2
    dpp_argmax_step<0x124, 0xf>(bv, bi);  // row_ror:4
    dpp_argmax_step<0x128, 0xf>(bv, bi);  // row_ror:8
    dpp_argmax_step<0x142, 0xa>(bv, bi);  // row_bcast15 -> rows 1,3
    dpp_argmax_step<0x143, 0xc>(bv, bi);  // row_bcast31 -> rows 2,3
    if ((t & 63) == 63) { redv[par][t >> 6] = bv; redi[par][t >> 6] = bi; }
    __syncthreads();
    bv = redv[par][0]; bi = redi[par][0];
#pragma unroll
    for (int w = 1; w < 8; ++w) {
      float ov = redv[par][w]; int oi = redi[par][w];
      if (ov > bv || (ov == bv && oi < bi)) { bv = ov; bi = oi; }
    }
    far = bi;
    par ^= 1;  // double-buffered red slots -> one barrier per iteration
  }
  __syncthreads();
  // Coalesced output writes from LDS staging.
  for (int f = t; f < 3 * S_; f += 512)
    nxyz[(size_t)b * 3 * S_ + f] = scent[f];        // [B][S][3]
  for (int s = t; s < S_; s += 512) {               // [B][3][S]
    out0[(size_t)b * 3 * S_ + s]          = scent[s * 3];
    out0[(size_t)b * 3 * S_ + S_ + s]     = scent[s * 3 + 1];
    out0[(size_t)b * 3 * S_ + 2 * S_ + s] = scent[s * 3 + 2];
  }
}

// ---------------------------------------------------------------------------
// Ball query: PROVEN EXACT in R6 (XLA-CPU f32 all-fma ordering). DO NOT
// MODIFY the arithmetic. Thread per query, serial scan, early break.
// ---------------------------------------------------------------------------
__global__ __launch_bounds__(64) void bq_fma_kernel(
    const float* __restrict__ xyz, const float* __restrict__ nxyz,
    int* __restrict__ idxb) {
#pragma clang fp contract(off)
  int q = blockIdx.x * 64 + threadIdx.x;
  int b = q >> 10;
  const float* xb = xyz + (size_t)b * 3 * N_;
  float cx = nxyz[(size_t)q * 3];
  float cy = nxyz[(size_t)q * 3 + 1];
  float cz = nxyz[(size_t)q * 3 + 2];
  float A = fmaf(cz, cz, fmaf(cy, cy, cx * cx));
  int* out = idxb + (size_t)q * K_;
  int found = 0, first_i = -1;
  for (int i = 0; i < N_; ++i) {
    float x = xb[i], y = xb[N_ + i], z = xb[2 * N_ + i];
    float Bv  = fmaf(z, z, fmaf(y, y, x * x));
    float dot = fmaf(cz, z, fmaf(cy, y, cx * x));
    float d = fmaf(-2.0f, dot, A + Bv);
    if (d <= 0.04f) {
      if (first_i < 0) first_i = i;
      out[found] = i;
      ++found;
      if (found >= K_) break;
    }
  }
  for (int s = found; s < K_; ++s) out[s] = first_i;
}

// ---------------------------------------------------------------------------
// Layer 0 conv (tiled, validated): gather -> 32x67 @ 67x64 -> pre f16 +
// per-block channel sum/sumsq partials. 128 thr, 4x4 register tile.
// ---------------------------------------------------------------------------
__global__ __launch_bounds__(128) void convA_kernel(
    const float* __restrict__ ptsT, const float* __restrict__ nxyz,
    const int* __restrict__ idxb, const float* __restrict__ w0,
    const float* __restrict__ b0, _Float16* __restrict__ pre,
    float* __restrict__ part) {
  __shared__ __align__(16) float sfeat[32 * 72];
  __shared__ __align__(16) float sw[64 * 76];
  __shared__ float red0[64 * 8], red1[64 * 8];
  __shared__ __align__(16) _Float16 sstage[2048];
  __shared__ int sidx[32];
  int g = blockIdx.x;
  int t = threadIdx.x;
  int b = g >> 10;
  if (t < 32) sidx[t] = idxb[(size_t)g * K_ + t];
  for (int f = t; f < 64 * 68; f += 128) {
    int c = f / 68, ci = f - c * 68;
    sw[c * 76 + ci] = (ci < 67) ? w0[c * 67 + ci] : 0.f;
  }
  const float* nx = nxyz + (size_t)g * 3;
  float ctr0 = nx[0], ctr1 = nx[1], ctr2 = nx[2];
  __syncthreads();
  for (int f = t; f < 32 * 68; f += 128) {
    int k = f / 68, ci = f - k * 68;
    float v = ptsT[(size_t)(b * N_ + sidx[k]) * 68 + ci];  // col 67 is 0
    if (ci == 0) v -= ctr0; else if (ci == 1) v -= ctr1; else if (ci == 2) v -= ctr2;
    sfeat[k * 72 + ci] = v;
  }
  __syncthreads();
  int kq = t & 7, cq = t >> 3;
  float acc[4][4] = {};
  for (int ci = 0; ci < 68; ci += 4) {
    float4 fv[4], wv[4];
#pragma unroll
    for (int kk = 0; kk < 4; ++kk) fv[kk] = *(const float4*)&sfeat[(kq + 8 * kk) * 72 + ci];
#pragma unroll
    for (int cc = 0; cc < 4; ++cc) wv[cc] = *(const float4*)&sw[(cq + 16 * cc) * 76 + ci];
#pragma unroll
    for (int kk = 0; kk < 4; ++kk)
#pragma unroll
      for (int cc = 0; cc < 4; ++cc)
        acc[kk][cc] += fv[kk].x * wv[cc].x + fv[kk].y * wv[cc].y +
                       fv[kk].z * wv[cc].z + fv[kk].w * wv[cc].w;
  }
#pragma unroll
  for (int cc = 0; cc < 4; ++cc) {
    int c = cq + 16 * cc;
    float bias = b0[c];
    float s1 = 0.f, s2 = 0.f;
#pragma unroll
    for (int kk = 0; kk < 4; ++kk) {
      float v = acc[kk][cc] + bias;
      sstage[(kq + 8 * kk) * 64 + c] = (_Float16)v;
      s1 += v; s2 += v * v;
    }
    red0[c * 8 + kq] = s1; red1[c * 8 + kq] = s2;
  }
  __syncthreads();
  if (t < 64) {
    float s1 = 0.f, s2 = 0.f;
#pragma unroll
    for (int qn = 0; qn < 8; ++qn) { s1 += red0[t * 8 + qn]; s2 += red1[t * 8 + qn]; }
    part[(size_t)g * 256 + t] = s1;
    part[(size_t)g * 256 + 64 + t] = s2;
  }
  uint4* dst = (uint4*)(pre + (size_t)g * 2048);
  const uint4* srcv = (const uint4*)sstage;
  dst[t] = srcv[t];
  dst[t + 128] = srcv[t + 128];
}

// ---------------------------------------------------------------------------
// Stats reduce v2 (R8): COALESCED. Thread t owns channel t; block r0 sums 64
// consecutive rows; one atomicAdd per (block, channel). Old version had lanes
// 1KB apart (one 64B line per lane per load -> ~270MB of line traffic).
// Requires accum pre-zeroed (hipMemsetAsync in kernel_launch).
// ---------------------------------------------------------------------------
__global__ __launch_bounds__(256) void red_kernel(
    const float* __restrict__ part, float* __restrict__ accum) {
  int t = threadIdx.x;
  size_t base = (size_t)blockIdx.x * 64 * 256 + t;
  float a = 0.f;
#pragma unroll 8
  for (int r = 0; r < 64; ++r) a += part[base + (size_t)r * 256];
  atomicAdd(accum + t, a);
}

// ---------------------------------------------------------------------------
// Layer 1 conv (tiled): BN0+relu on pre -> conv w1 -> pre2 + stats partials.
// ---------------------------------------------------------------------------
__global__ __launch_bounds__(128) void convB_kernel(
    const _Float16* __restrict__ pre, const float* __restrict__ accum,
    const float* __restrict__ gam, const float* __restrict__ bet,
    const float* __restrict__ w1, const float* __restrict__ b1,
    _Float16* __restrict__ pre2, float* __restrict__ part) {
  __shared__ __align__(16) float sfeat[32 * 72];
  __shared__ __align__(16) float sw[64 * 76];
  __shared__ float red0[64 * 8], red1[64 * 8];
  __shared__ __align__(16) _Float16 sstage[2048];
  __shared__ float ssc[64], ssh[64];
  int g = blockIdx.x;
  int t = threadIdx.x;
  if (t < 64) {
    float mu = accum[t] * (1.f / CNT_F);
    float var = accum[64 + t] * (1.f / CNT_F) - mu * mu;
    float sc = gam[t] / sqrtf(var + EPS_);
    ssc[t] = sc; ssh[t] = bet[t] - mu * sc;
  }
  for (int f = t; f < 64 * 64; f += 128) {
    int c = f >> 6, ci = f & 63;
    sw[c * 76 + ci] = w1[f];
  }
  __syncthreads();
  const _Float16* src = pre + (size_t)g * 2048;
  for (int f = t; f < 2048; f += 128) {
    int c = f & 63;
    float v = (float)src[f] * ssc[c] + ssh[c];
    sfeat[(f >> 6) * 72 + c] = fmaxf(v, 0.f);
  }
  __syncthreads();
  int kq = t & 7, cq = t >> 3;
  float acc[4][4] = {};
  for (int ci = 0; ci < 64; ci += 4) {
    float4 fv[4], wv[4];
#pragma unroll
    for (int kk = 0; kk < 4; ++kk) fv[kk] = *(const float4*)&sfeat[(kq + 8 * kk) * 72 + ci];
#pragma unroll
    for (int cc = 0; cc < 4; ++cc) wv[cc] = *(const float4*)&sw[(cq + 16 * cc) * 76 + ci];
#pragma unroll
    for (int kk = 0; kk < 4; ++kk)
#pragma unroll
      for (int cc = 0; cc < 4; ++cc)
        acc[kk][cc] += fv[kk].x * wv[cc].x + fv[kk].y * wv[cc].y +
                       fv[kk].z * wv[cc].z + fv[kk].w * wv[cc].w;
  }
#pragma unroll
  for (int cc = 0; cc < 4; ++cc) {
    int c = cq + 16 * cc;
    float bias = b1[c];
    float s1 = 0.f, s2 = 0.f;
#pragma unroll
    for (int kk = 0; kk < 4; ++kk) {
      float v = acc[kk][cc] + bias;
      sstage[(kq + 8 * kk) * 64 + c] = (_Float16)v;
      s1 += v; s2 += v * v;
    }
    red0[c * 8 + kq] = s1; red1[c * 8 + kq] = s2;
  }
  __syncthreads();
  if (t < 64) {
    float s1 = 0.f, s2 = 0.f;
#pragma unroll
    for (int qn = 0; qn < 8; ++qn) { s1 += red0[t * 8 + qn]; s2 += red1[t * 8 + qn]; }
    part[(size_t)g * 256 + t] = s1;
    part[(size_t)g * 256 + 64 + t] = s2;
  }
  uint4* dst = (uint4*)(pre2 + (size_t)g * 2048);
  const uint4* srcv = (const uint4*)sstage;
  dst[t] = srcv[t];
  dst[t + 128] = srcv[t + 128];
}

// ---------------------------------------------------------------------------
// Layer 2 conv (tiled): BN1+relu on pre2 -> conv w2 (128 out) -> stats
// partials + per-group pre-BN max/min over k (relu∘BN monotone).
// ---------------------------------------------------------------------------
__global__ __launch_bounds__(256) void convC_kernel(
    const _Float16* __restrict__ pre2, const float* __restrict__ accum,
    const float* __restrict__ gam, const float* __restrict__ bet,
    const float* __restrict__ w2, const float* __restrict__ b2,
    float* __restrict__ mm, float* __restrict__ part) {
  __shared__ __align__(16) float sfeat[32 * 72];
  __shared__ __align__(16) float sw[128 * 76];
  __shared__ float red0[128 * 8], red1[128 * 8];
  __shared__ float rmax[128 * 8], rmin[128 * 8];
  __shared__ float ssc[64], ssh[64];
  int g = blockIdx.x;
  int t = threadIdx.x;
  if (t < 64) {
    float mu = accum[t] * (1.f / CNT_F);
    float var = accum[64 + t] * (1.f / CNT_F) - mu * mu;
    float sc = gam[t] / sqrtf(var + EPS_);
    ssc[t] = sc; ssh[t] = bet[t] - mu * sc;
  }
  for (int f = t; f < 128 * 64; f += 256) {
    int c = f >> 6, ci = f & 63;
    sw[c * 76 + ci] = w2[f];
  }
  __syncthreads();
  const _Float16* src = pre2 + (size_t)g * 2048;
  for (int f = t; f < 2048; f += 256) {
    int c = f & 63;
    float v = (float)src[f] * ssc[c] + ssh[c];
    sfeat[(f >> 6) * 72 + c] = fmaxf(v, 0.f);
  }
  __syncthreads();
  int kq = t & 7, cq = t >> 3;  // cq 0..31
  float acc[4][4] = {};
  for (int ci = 0; ci < 64; ci += 4) {
    float4 fv[4], wv[4];
#pragma unroll
    for (int kk = 0; kk < 4; ++kk) fv[kk] = *(const float4*)&sfeat[(kq + 8 * kk) * 72 + ci];
#pragma unroll
    for (int cc = 0; cc < 4; ++cc) wv[cc] = *(const float4*)&sw[(cq + 32 * cc) * 76 + ci];
#pragma unroll
    for (int kk = 0; kk < 4; ++kk)
#pragma unroll
      for (int cc = 0; cc < 4; ++cc)
        acc[kk][cc] += fv[kk].x * wv[cc].x + fv[kk].y * wv[cc].y +
                       fv[kk].z * wv[cc].z + fv[kk].w * wv[cc].w;
  }
#pragma unroll
  for (int cc = 0; cc < 4; ++cc) {
    int c = cq + 32 * cc;
    float bias = b2[c];
    float s1 = 0.f, s2 = 0.f, mx = -3.4e38f, mn = 3.4e38f;
#pragma unroll
    for (int kk = 0; kk < 4; ++kk) {
      float v = acc[kk][cc] + bias;
      s1 += v; s2 += v * v;
      mx = fmaxf(mx, v); mn = fminf(mn, v);
    }
    red0[c * 8 + kq] = s1; red1[c * 8 + kq] = s2;
    rmax[c * 8 + kq] = mx; rmin[c * 8 + kq] = mn;
  }
  __syncthreads();
  if (t < 128) {
    float s1 = 0.f, s2 = 0.f, mx = -3.4e38f, mn = 3.4e38f;
#pragma unroll
    for (int qn = 0; qn < 8; ++qn) {
      s1 += red0[t * 8 + qn]; s2 += red1[t * 8 + qn];
      mx = fmaxf(mx, rmax[t * 8 + qn]); mn = fminf(mn, rmin[t * 8 + qn]);
    }
    part[(size_t)g * 256 + t] = s1;
    part[(size_t)g * 256 + 128 + t] = s2;
    mm[(size_t)g * 256 + t] = mx;
    mm[(size_t)g * 256 + 128 + t] = mn;
  }
}

// ---------------------------------------------------------------------------
// Final v2 (R8): coalesced. Block = (b, 64-s tile); read mm ROWS (consecutive
// c per lane), LDS transpose, write out[B,128,S] coalesced in s.
// ---------------------------------------------------------------------------
__global__ __launch_bounds__(256) void fin_kernel(
    const float* __restrict__ mm, const float* __restrict__ accum,
    const float* __restrict__ gam, const float* __restrict__ bet,
    float* __restrict__ out1) {
  __shared__ float tile[128 * 65];
  __shared__ float ssc[128], ssh[128];
  int blk = blockIdx.x;
  int b = blk >> 4;
  int s0 = (blk & 15) << 6;
  int t = threadIdx.x;
  if (t < 128) {
    float mu = accum[t] * (1.f / CNT_F);
    float var = accum[128 + t] * (1.f / CNT_F) - mu * mu;
    float sc = gam[t] / sqrtf(var + EPS_);
    ssc[t] = sc; ssh[t] = bet[t] - mu * sc;
  }
  __syncthreads();
  for (int f = t; f < 64 * 128; f += 256) {
    int sl = f >> 7, c = f & 127;
    const float* row = mm + (size_t)(b * S_ + s0 + sl) * 256;
    float sc = ssc[c];
    float v = (sc >= 0.f) ? row[c] : row[128 + c];
    tile[c * 65 + sl] = fmaxf(v * sc + ssh[c], 0.f);
  }
  __syncthreads();
  for (int f = t; f < 128 * 64; f += 256) {
    int c = f >> 6, sl = f & 63;
    out1[(size_t)b * 131072 + c * 1024 + s0 + sl] = tile[c * 65 + sl];
  }
}

// ---------------------------------------------------------------------------
extern "C" void kernel_launch(void* const* d_in, const int* in_sizes, int n_in,
                              void* d_out, int out_size, void* d_ws, size_t ws_size,
                              hipStream_t stream) {
  const float* xyz = (const float*)d_in[0];
  const float* pts = (const float*)d_in[1];
  const float* w0  = (const float*)d_in[2];
  const float* b0  = (const float*)d_in[3];
  const float* g0  = (const float*)d_in[4];
  const float* bt0 = (const float*)d_in[5];
  const float* w1  = (const float*)d_in[6];
  const float* b1  = (const float*)d_in[7];
  const float* g1  = (const float*)d_in[8];
  const float* bt1 = (const float*)d_in[9];
  const float* w2  = (const float*)d_in[10];
  const float* b2  = (const float*)d_in[11];
  const float* g2  = (const float*)d_in[12];
  const float* bt2 = (const float*)d_in[13];
  float* out = (float*)d_out;

  char* ws = (char*)d_ws;
  float*    nxyz  = (float*)(ws + OFF_NXYZ);
  int*      idxb  = (int*)(ws + OFF_IDX);
  float*    ptsT  = (float*)(ws + OFF_PTST);
  _Float16* pre   = (_Float16*)(ws + OFF_PRE);
  _Float16* pre2  = (_Float16*)(ws + OFF_PRE2);
  float*    part  = (float*)(ws + OFF_PART);
  float*    mm    = (float*)(ws + OFF_MM3);
  float*    accum = (float*)(ws + OFF_ACC);

  hipMemsetAsync(accum, 0, 3 * 256 * sizeof(float), stream);

  fps_kernel<<<B_, 512, 0, stream>>>(xyz, nxyz, out);
  transpose_kernel<<<B_ * (N_ / 64), 256, 0, stream>>>(xyz, pts, ptsT);
  bq_fma_kernel<<<(B_ * S_) / 64, 64, 0, stream>>>(xyz, nxyz, idxb);

  convA_kernel<<<B_ * S_, 128, 0, stream>>>(ptsT, nxyz, idxb, w0, b0, pre, part);
  red_kernel<<<256, 256, 0, stream>>>(part, accum);
  convB_kernel<<<B_ * S_, 128, 0, stream>>>(pre, accum, g0, bt0, w1, b1, pre2, part);
  red_kernel<<<256, 256, 0, stream>>>(part, accum + 256);
  convC_kernel<<<B_ * S_, 256, 0, stream>>>(pre2, accum + 256, g1, bt1, w2, b2, mm, part);
  red_kernel<<<256, 256, 0, stream>>>(part, accum + 512);
  fin_kernel<<<B_ * (S_ / 64), 256, 0, stream>>>(mm, accum + 512, g2, bt2,
                                                 out + B_ * 3 * S_);
}